// Round 5
// baseline (120.923 us; speedup 1.0000x reference)
//
#include <hip/hip_runtime.h>
#include <math.h>

// (N, Cin, Cout, S, H, W) = (4, 256, 256, 512, 64, 64)
#define NB 4
#define CC 256
#define SS 512
#define NL 6
#define SLOT_HW 65536   // 128 KB per weight slot, MFMA-A-fragment-packed
// ws layout (halfwords): slots 0..6 (conv + 6x mod_w[l]) = [0, 458752)
//   g table float[6144] at halfword offset 458752 (byte 917504)
#define G_OFF_HW   (7*SLOT_HW)

typedef __attribute__((ext_vector_type(8))) short s16x8;
typedef __attribute__((ext_vector_type(4))) float f32x4;
typedef __attribute__((ext_vector_type(2))) float f32x2;

__device__ __forceinline__ unsigned short f2bf(float f) {
    unsigned u = __builtin_bit_cast(unsigned, f);
    u += 0x7FFFu + ((u >> 16) & 1u);
    return (unsigned short)(u >> 16);
}
// packed RNE f32->bf16 pair: dst[15:0]=cvt(lo), dst[31:16]=cvt(hi)
__device__ __forceinline__ unsigned cvt_pk_bf16(float lo, float hi) {
    unsigned r;
    asm("v_cvt_pk_bf16_f32 %0, %1, %2" : "=v"(r) : "v"(lo), "v"(hi));
    return r;
}
// gelu_exact(x) ~= x*sigmoid(1.5957691216*(x+0.044715x^3)), |err|<3e-3
__device__ __forceinline__ float gelu_fast(float x) {
    float u = x * (1.0f + 0.044715f * x * x);
    float e = __expf(-1.5957691216f * u);
    return x * __builtin_amdgcn_rcpf(1.0f + e);
}

// Fragment-packed weight layout, per 256x256 GEMM slot (128 KB):
// fragment f = (m>>4)*8 + (k>>5); inside: halfword offset
//   ((k>>3)&3)*128 + (m&15)*8 + (k&7)
// wave A-fragment read = slot + f*512 + lane*8 (16 B/lane contiguous).

// ---------------------------------------------------------------------------
// Prep: g-factorization.  wmod rows are uniformly scaled mod_w rows:
//   h = normalize(mod_w*(s+1)) @ y1  ==  g[l,b,m] * (mod_w[l] @ y1),
//   g = t*rsqrt(t^2*Q + eps), t = s[b,m]+1, Q[l,m] = sum_k mod_w[l][m,k]^2.
// => only 7 batch-independent A-slots (conv + 6 mod_w) + 6144-float g table.
__global__ __launch_bounds__(256) void prep_kernel(
    const float* __restrict__ y, const float* __restrict__ aw,
    const float* __restrict__ ab, const float* __restrict__ mw,
    const float* __restrict__ cw, unsigned short* __restrict__ wsBF)
{
    int w = threadIdx.x >> 6, lane = threadIdx.x & 63;
    float* gtab = (float*)(wsBF + G_OFF_HW);

    if (blockIdx.x < 448) {            // slot packing: row = slot*256 + m
        int row = blockIdx.x*4 + w;    // 0..1791
        int sl  = row >> 8, m = row & 255;
        const float* src = (sl == 0) ? (cw + (size_t)m*CC)
                                     : (mw + ((size_t)(sl-1)*CC + m)*CC);
        unsigned short* dst = wsBF + (size_t)sl*SLOT_HW;
#pragma unroll
        for (int u = 0; u < 4; ++u) {
            int k = lane + 64*u;
            int f = (m >> 4)*8 + (k >> 5);
            int hw = f*512 + ((k >> 3) & 3)*128 + (m & 15)*8 + (k & 7);
            dst[hw] = f2bf(src[k]);
        }
        return;
    }

    int r  = (blockIdx.x - 448)*4 + w; // 0..1535 = (layer, out-channel)
    int pl = r >> 8, po = r & 255;

    const float* awr = aw + (size_t)(pl*CC + po)*SS;
    float s[4] = {0.f, 0.f, 0.f, 0.f};
#pragma unroll
    for (int j = 0; j < 8; ++j) {
        int idx = lane + 64*j;
        float a = awr[idx];
#pragma unroll
        for (int b = 0; b < 4; ++b) s[b] += a * y[(size_t)b*SS + idx];
    }
    const float* mwr = mw + ((size_t)pl*CC + po)*CC;
    float qs = 0.f;
#pragma unroll
    for (int u = 0; u < 4; ++u) { float v = mwr[lane + 64*u]; qs += v*v; }
#pragma unroll
    for (int off = 32; off; off >>= 1) {
#pragma unroll
        for (int b = 0; b < 4; ++b) s[b] += __shfl_xor(s[b], off);
        qs += __shfl_xor(qs, off);
    }
    float abv = ab[pl*CC + po];
    if (lane < 4) {
        float t = s[lane] + abv + 1.0f;
        gtab[pl*1024 + lane*256 + po] = t * (1.0f / sqrtf(t*t*qs + 1e-8f));
    }
}

// ---------------------------------------------------------------------------
// Fused: one block = (batch, FULL 64-px strip, all 256 channels). Grid 256,
// 1024 thr (16 waves = 8 m-groups x 2 n-halves), 132 KB LDS -> 1 block/CU
// (16 waves/CU, same occupancy as before). The two waves sharing an m-group
// issue IDENTICAL A-slot addresses inside the same barrier phase -> L1
// dedupes the second read -> L2 A-traffic ~halves vs 512x512 structure.
#define BFRAG64(buf, kq, nt, kcl) \
    (lds + (buf)*32768 + ((((kq)*4 + (nt))*2 + (kcl)))*1024)

__global__ __launch_bounds__(1024, 4) void fused_kernel(
    const float* __restrict__ x, const float* __restrict__ cb,
    const unsigned short* __restrict__ wsBF, float* __restrict__ out)
{
    // LDS 135168 B: layer-B dbuf [0,64K) | conv region @65536:
    //   xS f32[256][68] (69632 B) during conv staging, then S2 f32[128][65]
    //   (33280 B) in the epilogue (xS dead by then). Conv B frags in buf0.
    __shared__ __align__(16) unsigned char lds[135168];
    float* xS = (float*)(lds + 65536);
    float* S2 = (float*)(lds + 65536);
    const float* gtab = (const float*)(wsBF + G_OFF_HW);

    const int tid  = threadIdx.x;
    const int lane = tid & 63;
    const int w    = tid >> 6;     // wave 0..15
    const int wm   = w & 7;        // m-group: rows [32wm, 32wm+32)
    const int wn   = w >> 3;       // n-half: cols [32wn, 32wn+32) of strip
    const int l15  = lane & 15;
    const int q    = lane >> 4;    // 0..3

    // XCD round-robin (%8) -> each XCD serves exactly one batch
    const int b     = blockIdx.x & 3;          // 0..3
    const int strip = blockIdx.x >> 2;         // 0..63 (source row h)
    const int n0    = strip * 64;              // 64-px window (full row)

    float y1[2][2][4], y2[2][2][4];
    f32x4 acc[2][2];

    // ---------------- conv GEMM:  acc = cw @ x[b], single-shot ----------------
#pragma unroll
    for (int t = 0; t < 2; ++t)
#pragma unroll
        for (int s = 0; s < 2; ++s) acc[t][s] = 0;

    // issue x window loads (HBM) FIRST, then conv A-prefetch (L2) so the
    // slot-0 latency hides under LDS staging + transpose-build
    float4 xr[4];
#pragma unroll
    for (int p = 0; p < 4; ++p) {
        int row = (tid >> 4) + 64*p, c4 = (tid & 15) * 4;
        xr[p] = *(const float4*)&x[((size_t)(b*CC + row))*4096 + n0 + c4];
    }
    s16x8 aS[8][2];
#pragma unroll
    for (int p = 0; p < 4; ++p)
#pragma unroll
    for (int t = 0; t < 2; ++t)
        aS[p][t] = *(const s16x8*)(wsBF + (size_t)(((2*wm+t)*8 + p)*512) + lane*8);

#pragma unroll
    for (int p = 0; p < 4; ++p) {      // land x into LDS
        int row = (tid >> 4) + 64*p, c4 = (tid & 15) * 4;
        *(float4*)&xS[row*68 + c4] = xr[p];
    }
    __syncthreads();
    {   // transpose-read (2-way, free) -> bf16 -> ALL conv-B frags (buf0)
        int n = tid & 63, k0 = (tid >> 6) * 16;
        int nt = n >> 4, n15 = n & 15;
#pragma unroll
        for (int j = 0; j < 4; ++j) {
            int k = k0 + 4*j;
            float v0 = xS[(k+0)*68 + n], v1 = xS[(k+1)*68 + n];
            float v2 = xS[(k+2)*68 + n], v3 = xS[(k+3)*68 + n];
            uint2 hv; hv.x = cvt_pk_bf16(v0, v1); hv.y = cvt_pk_bf16(v2, v3);
            int kq = k >> 6, kcl = (k >> 5) & 1, qq = (k >> 3) & 3, jb = k & 7;
            *(uint2*)(BFRAG64(0,kq,nt,kcl) + (16*qq + n15)*16 + jb*2) = hv;
        }
    }
    __syncthreads();
    {   // one 8-step MFMA phase, A prefetched 4 ahead
        const unsigned short* slot = wsBF;
        __builtin_amdgcn_s_setprio(1);
#pragma unroll
        for (int step = 0; step < 8; ++step) {
            if (step < 4) {
#pragma unroll
                for (int t = 0; t < 2; ++t)
                    aS[step+4][t] = *(const s16x8*)(slot + (size_t)(((2*wm+t)*8 + step+4)*512) + lane*8);
            }
            int kq = step >> 1, kcl = step & 1;
#pragma unroll
            for (int s = 0; s < 2; ++s) {
                s16x8 bh = *(const s16x8*)(BFRAG64(0,kq,wn*2+s,kcl) + lane*16);
#pragma unroll
                for (int t = 0; t < 2; ++t)
                    acc[t][s] = __builtin_amdgcn_mfma_f32_16x16x32_bf16(aS[step][t], bh, acc[t][s], 0, 0, 0);
            }
        }
        __builtin_amdgcn_s_setprio(0);
    }

    // conv epilogue: bias + channel-duplication remap via S2 (xS region, dead).
    // x1[c] = conv[c>>1]+cb, x2[c] = conv[128+(c>>1)]+cb
#pragma unroll
    for (int pass = 0; pass < 2; ++pass) {
        __syncthreads();
        if ((wm >> 2) == pass) {           // waves owning m in [128pass, +128)
#pragma unroll
            for (int t = 0; t < 2; ++t)
#pragma unroll
            for (int s = 0; s < 2; ++s)
#pragma unroll
            for (int r = 0; r < 4; ++r) {
                int m  = 32*wm + 16*t + 4*q + r;
                int nl = wn*32 + 16*s + l15;
                S2[(m - 128*pass)*65 + nl] = acc[t][s][r] + cb[m];
            }
        }
        __syncthreads();
#pragma unroll
        for (int t = 0; t < 2; ++t)
#pragma unroll
        for (int s = 0; s < 2; ++s)
#pragma unroll
        for (int r = 0; r < 4; ++r) {
            int c  = 32*wm + 16*t + 4*q + r;
            int nl = wn*32 + 16*s + l15;
            float v = S2[(c >> 1)*65 + nl];
            if (pass == 0) { y1[t][s][r] = v; }
            else           { y2[t][s][r] = v; y1[t][s][r] += v; }
        }
    }
    // y1 = x1+x2, y2 = x2.  No barrier needed: layer-0 staging targets buf0
    // [0,32K), disjoint from S2 @65536; buf0's conv reads were fenced by the
    // epilogue's first __syncthreads.

    // ---------------- 6 layers: ONE barrier per layer (B dbuf) ----------------
    for (int l = 0; l < NL; ++l) {
        const int buf = l & 1;
        const unsigned short* slot = wsBF + (size_t)(1 + l)*SLOT_HW; // batch-indep
#pragma unroll
        for (int t = 0; t < 2; ++t)
#pragma unroll
            for (int s = 0; s < 2; ++s) acc[t][s] = 0;

        // issue A-prefetch (depth 4) + g loads FIRST (L2 latency hides under
        // the B-stage packing below)
#pragma unroll
        for (int p = 0; p < 4; ++p)
#pragma unroll
        for (int t = 0; t < 2; ++t)
            aS[p][t] = *(const s16x8*)(slot + (size_t)(((2*wm+t)*8 + p)*512) + lane*8);
        float4 gv[2];
#pragma unroll
        for (int t = 0; t < 2; ++t)
            gv[t] = *(const float4*)&gtab[l*1024 + b*256 + 32*wm + 16*t + 4*q];

        // stage B (bf16) from y1 regs: wave wm's rows = k-slice [32wm,32wm+32)
        {
            int kq = wm >> 1, kcl = wm & 1, jb = 4*(q & 1);
#pragma unroll
            for (int t = 0; t < 2; ++t) {
                int qq = 2*t + (q >> 1);
#pragma unroll
                for (int s = 0; s < 2; ++s) {
                    uint2 hv;
                    hv.x = cvt_pk_bf16(y1[t][s][0], y1[t][s][1]);
                    hv.y = cvt_pk_bf16(y1[t][s][2], y1[t][s][3]);
                    *(uint2*)(BFRAG64(buf,kq,wn*2+s,kcl) + (16*qq + l15)*16 + jb*2) = hv;
                }
            }
        }
        __syncthreads();
        // ONE long MFMA phase: 8 steps, A prefetched 4 steps ahead
        __builtin_amdgcn_s_setprio(1);
#pragma unroll
        for (int step = 0; step < 8; ++step) {
            if (step < 4) {
#pragma unroll
                for (int t = 0; t < 2; ++t)
                    aS[step+4][t] = *(const s16x8*)(slot + (size_t)(((2*wm+t)*8 + step+4)*512) + lane*8);
            }
            int kq = step >> 1, kcl = step & 1;
#pragma unroll
            for (int s = 0; s < 2; ++s) {
                s16x8 bh = *(const s16x8*)(BFRAG64(buf,kq,wn*2+s,kcl) + lane*16);
#pragma unroll
                for (int t = 0; t < 2; ++t)
                    acc[t][s] = __builtin_amdgcn_mfma_f32_16x16x32_bf16(aS[step][t], bh, acc[t][s], 0, 0, 0);
            }
        }
        __builtin_amdgcn_s_setprio(0);
        // h = g*acc; y2 += gelu(h); y1 += y2 (next layer), skip on last.
        // No trailing barrier: next layer stages the OTHER buffer.
#pragma unroll
        for (int t = 0; t < 2; ++t)
#pragma unroll
        for (int s = 0; s < 2; ++s)
#pragma unroll
        for (int r = 0; r < 4; ++r) {
            y2[t][s][r] += gelu_fast(acc[t][s][r] * gv[t][r]);
            if (l < NL - 1) y1[t][s][r] += y2[t][s][r];
        }
    }

    // ---------------- out = 0.5*(y1+y2), 2x2 upsample (nontemporal) --------
#pragma unroll
    for (int t = 0; t < 2; ++t)
#pragma unroll
    for (int s = 0; s < 2; ++s)
#pragma unroll
    for (int r = 0; r < 4; ++r) {
        int ch  = 32*wm + 16*t + 4*q + r;
        int wpx = wn*32 + 16*s + l15;         // 0..63 source col
        float v = 0.5f*(y1[t][s][r] + y2[t][s][r]);
        f32x2 vv = {v, v};
        size_t base = (((size_t)(b*CC + ch)*128 + 2*strip))*128 + 2*wpx;
        __builtin_nontemporal_store(vv, (f32x2*)&out[base]);
        __builtin_nontemporal_store(vv, (f32x2*)&out[base + 128]);
    }
}

extern "C" void kernel_launch(void* const* d_in, const int* in_sizes, int n_in,
                              void* d_out, int out_size, void* d_ws, size_t ws_size,
                              hipStream_t stream) {
    const float* x  = (const float*)d_in[0];
    const float* y  = (const float*)d_in[1];
    const float* cw = (const float*)d_in[2];
    const float* cb = (const float*)d_in[3];
    const float* aw = (const float*)d_in[4];
    const float* ab = (const float*)d_in[5];
    const float* mw = (const float*)d_in[6];
    float* out = (float*)d_out;

    unsigned short* wsBF = (unsigned short*)d_ws;   // 7 slots + g table < 1 MB

    prep_kernel<<<832, 256, 0, stream>>>(y, aw, ab, mw, cw, wsBF);
    fused_kernel<<<256, 1024, 0, stream>>>(x, cb, wsBF, out);
}

// Round 6
// 120.194 us; speedup vs baseline: 1.0061x; 1.0061x over previous
//
#include <hip/hip_runtime.h>
#include <math.h>

// (N, Cin, Cout, S, H, W) = (4, 256, 256, 512, 64, 64)
#define NB 4
#define CC 256
#define SS 512
#define NL 6
#define SLOT_HW 65536   // 128 KB per weight slot, MFMA-A-fragment-packed
// ws layout (halfwords): slots 0..6 (conv + 6x mod_w[l]) = [0, 458752)
//   g table float[6144] at halfword offset 458752 (byte 917504)
#define G_OFF_HW   (7*SLOT_HW)

typedef __attribute__((ext_vector_type(8))) short s16x8;
typedef __attribute__((ext_vector_type(4))) float f32x4;
typedef __attribute__((ext_vector_type(2))) float f32x2;

// keep a 128-bit vector live (forces the load to issue+complete here, not at use)
#define PIN(v) asm volatile("" :: "v"(v))

__device__ __forceinline__ unsigned short f2bf(float f) {
    unsigned u = __builtin_bit_cast(unsigned, f);
    u += 0x7FFFu + ((u >> 16) & 1u);
    return (unsigned short)(u >> 16);
}
// packed RNE f32->bf16 pair: dst[15:0]=cvt(lo), dst[31:16]=cvt(hi)
__device__ __forceinline__ unsigned cvt_pk_bf16(float lo, float hi) {
    unsigned r;
    asm("v_cvt_pk_bf16_f32 %0, %1, %2" : "=v"(r) : "v"(lo), "v"(hi));
    return r;
}
// gelu_exact(x) ~= x*sigmoid(1.5957691216*(x+0.044715x^3)), |err|<3e-3
__device__ __forceinline__ float gelu_fast(float x) {
    float u = x * (1.0f + 0.044715f * x * x);
    float e = __expf(-1.5957691216f * u);
    return x * __builtin_amdgcn_rcpf(1.0f + e);
}

// Fragment-packed weight layout, per 256x256 GEMM slot (128 KB):
// fragment f = (m>>4)*8 + (k>>5); inside: halfword offset
//   ((k>>3)&3)*128 + (m&15)*8 + (k&7)
// wave A-fragment read = slot + f*512 + lane*8 (16 B/lane contiguous).

// ---------------------------------------------------------------------------
// Prep: g-factorization.  wmod rows are uniformly scaled mod_w rows:
//   h = normalize(mod_w*(s+1)) @ y1  ==  g[l,b,m] * (mod_w[l] @ y1),
//   g = t*rsqrt(t^2*Q + eps), t = s[b,m]+1, Q[l,m] = sum_k mod_w[l][m,k]^2.
// => only 7 batch-independent A-slots (conv + 6 mod_w) + 6144-float g table.
__global__ __launch_bounds__(256) void prep_kernel(
    const float* __restrict__ y, const float* __restrict__ aw,
    const float* __restrict__ ab, const float* __restrict__ mw,
    const float* __restrict__ cw, unsigned short* __restrict__ wsBF)
{
    int w = threadIdx.x >> 6, lane = threadIdx.x & 63;
    float* gtab = (float*)(wsBF + G_OFF_HW);

    if (blockIdx.x < 448) {            // slot packing: row = slot*256 + m
        int row = blockIdx.x*4 + w;    // 0..1791
        int sl  = row >> 8, m = row & 255;
        const float* src = (sl == 0) ? (cw + (size_t)m*CC)
                                     : (mw + ((size_t)(sl-1)*CC + m)*CC);
        unsigned short* dst = wsBF + (size_t)sl*SLOT_HW;
#pragma unroll
        for (int u = 0; u < 4; ++u) {
            int k = lane + 64*u;
            int f = (m >> 4)*8 + (k >> 5);
            int hw = f*512 + ((k >> 3) & 3)*128 + (m & 15)*8 + (k & 7);
            dst[hw] = f2bf(src[k]);
        }
        return;
    }

    int r  = (blockIdx.x - 448)*4 + w; // 0..1535 = (layer, out-channel)
    int pl = r >> 8, po = r & 255;

    const float* awr = aw + (size_t)(pl*CC + po)*SS;
    float s[4] = {0.f, 0.f, 0.f, 0.f};
#pragma unroll
    for (int j = 0; j < 8; ++j) {
        int idx = lane + 64*j;
        float a = awr[idx];
#pragma unroll
        for (int b = 0; b < 4; ++b) s[b] += a * y[(size_t)b*SS + idx];
    }
    const float* mwr = mw + ((size_t)pl*CC + po)*CC;
    float qs = 0.f;
#pragma unroll
    for (int u = 0; u < 4; ++u) { float v = mwr[lane + 64*u]; qs += v*v; }
#pragma unroll
    for (int off = 32; off; off >>= 1) {
#pragma unroll
        for (int b = 0; b < 4; ++b) s[b] += __shfl_xor(s[b], off);
        qs += __shfl_xor(qs, off);
    }
    float abv = ab[pl*CC + po];
    if (lane < 4) {
        float t = s[lane] + abv + 1.0f;
        gtab[pl*1024 + lane*256 + po] = t * (1.0f / sqrtf(t*t*qs + 1e-8f));
    }
}

// ---------------------------------------------------------------------------
// Fused: one block = (batch, 32-px half-strip, all 256 channels). Grid 512,
// 68 KB LDS -> 2 blocks/CU (cross-block drift covers barrier stalls). Wave w
// owns m=[32w,32w+32), all n=32. 9 barriers total: xS, frags, conv-epilogue,
// 6 layers. A-prefetch PINNED pre-barrier so L2 latency hides under stage+
// rendezvous, not the MFMA phase.
#define BFRAGL(buf, kq, nt, kcl) \
    (lds + (buf)*16384 + ((((kq)*2 + (nt))*2 + (kcl)))*1024)

__global__ __launch_bounds__(512, 4) void fused_kernel(
    const float* __restrict__ x, const float* __restrict__ cb,
    const unsigned short* __restrict__ wsBF, float* __restrict__ out)
{
    // LDS 69632 B: layer-B dbuf [0,32K) | conv region @32768: xS f32[256][36]
    // (36864 B) during conv staging, then S2 f32[256][33] (33792 B) in the
    // single-pass epilogue (xS dead by then). Conv B frags live in buf0.
    __shared__ __align__(16) unsigned char lds[69632];
    float* xS = (float*)(lds + 32768);
    float* S2 = (float*)(lds + 32768);
    const float* gtab = (const float*)(wsBF + G_OFF_HW);

    const int tid  = threadIdx.x;
    const int lane = tid & 63;
    const int w    = tid >> 6;     // wave 0..7: owns m-rows [32w, 32w+32)
    const int l15  = lane & 15;
    const int q    = lane >> 4;    // 0..3

    // XCD swizzle: blockIdx%8 -> (batch, half) per XCD; weights L2-resident
    const int bswz  = blockIdx.x & 7;
    const int b     = bswz >> 1;               // 0..3
    const int half  = bswz & 1;                // 0..1
    const int strip = blockIdx.x >> 3;         // 0..63
    const int n0    = strip * 64 + half * 32;  // 32-px window

    float y1[2][2][4], y2[2][2][4];
    f32x4 acc[2][2];

    // ---------------- conv GEMM:  acc = cw @ x[b], single-shot ----------------
#pragma unroll
    for (int t = 0; t < 2; ++t)
#pragma unroll
        for (int s = 0; s < 2; ++s) acc[t][s] = 0;

    // issue x window loads (HBM) FIRST, then conv A-prefetch (L2) so the
    // slot-0 latency hides under LDS staging + transpose-build
    float4 xr[4];
#pragma unroll
    for (int p = 0; p < 4; ++p) {
        int row = (tid >> 3) + 64*p, c4 = (tid & 7) * 4;
        xr[p] = *(const float4*)&x[((size_t)(b*CC + row))*4096 + n0 + c4];
    }
    s16x8 aS[8][2];
#pragma unroll
    for (int p = 0; p < 4; ++p)
#pragma unroll
    for (int t = 0; t < 2; ++t)
        aS[p][t] = *(const s16x8*)(wsBF + (size_t)(((2*w+t)*8 + p)*512) + lane*8);

#pragma unroll
    for (int p = 0; p < 4; ++p) {      // land x into LDS
        int row = (tid >> 3) + 64*p, c4 = (tid & 7) * 4;
        *(float4*)&xS[row*36 + c4] = xr[p];
    }
    __syncthreads();
    {   // transpose-read (conflict-free) -> bf16 -> ALL conv-B frags (buf0)
        int n = tid & 31, k0 = (tid >> 5) * 16;
        int nt = n >> 4, n15 = n & 15;
#pragma unroll
        for (int j = 0; j < 4; ++j) {
            int k = k0 + 4*j;
            float v0 = xS[(k+0)*36 + n], v1 = xS[(k+1)*36 + n];
            float v2 = xS[(k+2)*36 + n], v3 = xS[(k+3)*36 + n];
            uint2 hv; hv.x = cvt_pk_bf16(v0, v1); hv.y = cvt_pk_bf16(v2, v3);
            int kq = k >> 6, kcl = (k >> 5) & 1, qq = (k >> 3) & 3, jb = k & 7;
            *(uint2*)(BFRAGL(0,kq,nt,kcl) + (16*qq + n15)*16 + jb*2) = hv;
        }
    }
    // pin the depth-4 A prefetch: loads complete here, under the build+barrier
#pragma unroll
    for (int p = 0; p < 4; ++p) { PIN(aS[p][0]); PIN(aS[p][1]); }
    __syncthreads();
    {   // one 8-step MFMA phase, A steps 4-7 loaded in-loop
        const unsigned short* slot = wsBF;
        __builtin_amdgcn_s_setprio(1);
#pragma unroll
        for (int step = 0; step < 8; ++step) {
            if (step < 4) {
#pragma unroll
                for (int t = 0; t < 2; ++t)
                    aS[step+4][t] = *(const s16x8*)(slot + (size_t)(((2*w+t)*8 + step+4)*512) + lane*8);
            }
            int kq = step >> 1, kcl = step & 1;
#pragma unroll
            for (int s = 0; s < 2; ++s) {
                s16x8 bh = *(const s16x8*)(BFRAGL(0,kq,s,kcl) + lane*16);
#pragma unroll
                for (int t = 0; t < 2; ++t)
                    acc[t][s] = __builtin_amdgcn_mfma_f32_16x16x32_bf16(aS[step][t], bh, acc[t][s], 0, 0, 0);
            }
        }
        __builtin_amdgcn_s_setprio(0);
    }

    // conv epilogue, SINGLE PASS: every wave writes its m-rows into S2[256][33]
    // (xS dead: last read fenced by the pre-MFMA barrier), one barrier, then
    // read both channel-dup halves.  x1[c]=conv[c>>1]+cb, x2[c]=conv[128+(c>>1)]+cb
#pragma unroll
    for (int t = 0; t < 2; ++t)
#pragma unroll
    for (int s = 0; s < 2; ++s)
#pragma unroll
    for (int r = 0; r < 4; ++r) {
        int m  = 32*w + 16*t + 4*q + r;
        int nl = 16*s + l15;
        S2[m*33 + nl] = acc[t][s][r] + cb[m];
    }
    __syncthreads();
#pragma unroll
    for (int t = 0; t < 2; ++t)
#pragma unroll
    for (int s = 0; s < 2; ++s)
#pragma unroll
    for (int r = 0; r < 4; ++r) {
        int c  = 32*w + 16*t + 4*q + r;
        int nl = 16*s + l15;
        float a  = S2[(c >> 1)*33 + nl];
        float bb = S2[(128 + (c >> 1))*33 + nl];
        y1[t][s][r] = a + bb;          // x1 + x2
        y2[t][s][r] = bb;              // x2
    }
    // Layer-0 staging (buf0) is safe: every wave passed the barrier above only
    // after finishing its conv MFMA (all buf0 reads done).

    // ---------------- 6 layers: ONE barrier per layer (B dbuf) ----------------
    for (int l = 0; l < NL; ++l) {
        const int buf = l & 1;
        const unsigned short* slot = wsBF + (size_t)(1 + l)*SLOT_HW; // batch-indep
#pragma unroll
        for (int t = 0; t < 2; ++t)
#pragma unroll
            for (int s = 0; s < 2; ++s) acc[t][s] = 0;

        // issue A-prefetch (depth 4) + g loads FIRST (L2 latency hides under
        // the B-stage packing below + barrier rendezvous)
#pragma unroll
        for (int p = 0; p < 4; ++p)
#pragma unroll
        for (int t = 0; t < 2; ++t)
            aS[p][t] = *(const s16x8*)(slot + (size_t)(((2*w+t)*8 + p)*512) + lane*8);
        float4 gv[2];
#pragma unroll
        for (int t = 0; t < 2; ++t)
            gv[t] = *(const float4*)&gtab[l*1024 + b*256 + 32*w + 16*t + 4*q];

        // stage B (bf16) from y1 regs: wave w's rows = k-slice [32w,32w+32)
        {
            int kq = w >> 1, kcl = w & 1, jb = 4*(q & 1);
#pragma unroll
            for (int t = 0; t < 2; ++t) {
                int qq = 2*t + (q >> 1);
#pragma unroll
                for (int s = 0; s < 2; ++s) {
                    uint2 hv;
                    hv.x = cvt_pk_bf16(y1[t][s][0], y1[t][s][1]);
                    hv.y = cvt_pk_bf16(y1[t][s][2], y1[t][s][3]);
                    *(uint2*)(BFRAGL(buf,kq,s,kcl) + (16*qq + l15)*16 + jb*2) = hv;
                }
            }
        }
        // pin prefetch: A loads drain here (overlapped with stage), not in MFMA
#pragma unroll
        for (int p = 0; p < 4; ++p) { PIN(aS[p][0]); PIN(aS[p][1]); }
        __syncthreads();
        // ONE long MFMA phase: 8 steps, steps 4-7 A loaded in-loop
        __builtin_amdgcn_s_setprio(1);
#pragma unroll
        for (int step = 0; step < 8; ++step) {
            if (step < 4) {
#pragma unroll
                for (int t = 0; t < 2; ++t)
                    aS[step+4][t] = *(const s16x8*)(slot + (size_t)(((2*w+t)*8 + step+4)*512) + lane*8);
            }
            int kq = step >> 1, kcl = step & 1;
#pragma unroll
            for (int s = 0; s < 2; ++s) {
                s16x8 bh = *(const s16x8*)(BFRAGL(buf,kq,s,kcl) + lane*16);
#pragma unroll
                for (int t = 0; t < 2; ++t)
                    acc[t][s] = __builtin_amdgcn_mfma_f32_16x16x32_bf16(aS[step][t], bh, acc[t][s], 0, 0, 0);
            }
        }
        __builtin_amdgcn_s_setprio(0);

        if (l < NL - 1) {
            // h = g*acc; y2 += gelu(h); y1 += y2 for next layer
#pragma unroll
            for (int t = 0; t < 2; ++t)
#pragma unroll
            for (int s = 0; s < 2; ++s)
#pragma unroll
            for (int r = 0; r < 4; ++r) {
                y2[t][s][r] += gelu_fast(acc[t][s][r] * gv[t][r]);
                y1[t][s][r] += y2[t][s][r];
            }
        } else {
            // LAST layer: fuse epilogue into the 2x2-upsample store
#pragma unroll
            for (int t = 0; t < 2; ++t)
#pragma unroll
            for (int s = 0; s < 2; ++s)
#pragma unroll
            for (int r = 0; r < 4; ++r) {
                float yf = y2[t][s][r] + gelu_fast(acc[t][s][r] * gv[t][r]);
                float v  = 0.5f*(y1[t][s][r] + yf);
                int ch  = 32*w + 16*t + 4*q + r;
                int wpx = half*32 + 16*s + l15;       // 0..63 source col
                f32x2 vv = {v, v};
                size_t base = (((size_t)(b*CC + ch)*128 + 2*strip))*128 + 2*wpx;
                __builtin_nontemporal_store(vv, (f32x2*)&out[base]);
                __builtin_nontemporal_store(vv, (f32x2*)&out[base + 128]);
            }
        }
    }
}

extern "C" void kernel_launch(void* const* d_in, const int* in_sizes, int n_in,
                              void* d_out, int out_size, void* d_ws, size_t ws_size,
                              hipStream_t stream) {
    const float* x  = (const float*)d_in[0];
    const float* y  = (const float*)d_in[1];
    const float* cw = (const float*)d_in[2];
    const float* cb = (const float*)d_in[3];
    const float* aw = (const float*)d_in[4];
    const float* ab = (const float*)d_in[5];
    const float* mw = (const float*)d_in[6];
    float* out = (float*)d_out;

    unsigned short* wsBF = (unsigned short*)d_ws;   // 7 slots + g table < 1 MB

    prep_kernel<<<832, 256, 0, stream>>>(y, aw, ab, mw, cw, wsBF);
    fused_kernel<<<512, 512, 0, stream>>>(x, cb, wsBF, out);
}